// Round 1
// baseline (273.795 us; speedup 1.0000x reference)
//
#include <hip/hip_runtime.h>

#define NCOL 17
#define BLK  256

__global__ __launch_bounds__(BLK) void bsp_prime_kernel(
    const float* __restrict__ x, float* __restrict__ out, int n) {
    // C(15,k)
    const float C15[16] = {1.f, 15.f, 105.f, 455.f, 1365.f, 3003.f, 5005.f, 6435.f,
                           6435.f, 5005.f, 3003.f, 1365.f, 455.f, 105.f, 15.f, 1.f};

    __shared__ float tile[BLK * NCOL];  // 17408 B

    const int t = threadIdx.x;
    const int i = blockIdx.x * BLK + t;

    float y = (i < n) ? x[i] : 0.5f;
    // Reference's 0*log(0)=NaN -> zeroed rows at exact endpoints
    const bool edge = (y <= 0.0f) || (y >= 1.0f);
    const float omy = 1.0f - y;

    float yp[NCOL], op[NCOL];
    yp[0] = 1.0f;
    op[0] = 1.0f;
#pragma unroll
    for (int k = 1; k < NCOL; ++k) {
        yp[k] = yp[k - 1] * y;
        op[k] = op[k - 1] * omy;
    }

#pragma unroll
    for (int m = 0; m < NCOL; ++m) {
        float first = (m >= 1)  ? C15[m - 1] * yp[m - 1] * op[16 - m] : 0.0f;
        float sec   = (m <= 15) ? C15[m]     * yp[m]     * op[15 - m] : 0.0f;
        float v = 16.0f * (first - sec);
        // LDS write: stride-17 floats per lane -> gcd(17,32)=1 -> conflict-free
        tile[t * NCOL + m] = edge ? 0.0f : v;
    }

    __syncthreads();

    // Coalesced drain: block covers a contiguous 4352-float span of out
    const long long base  = (long long)blockIdx.x * (BLK * NCOL);
    const long long total = (long long)n * NCOL;
#pragma unroll
    for (int k = 0; k < NCOL; ++k) {
        long long idx = base + (long long)k * BLK + t;
        if (idx < total) out[idx] = tile[k * BLK + t];
    }
}

extern "C" void kernel_launch(void* const* d_in, const int* in_sizes, int n_in,
                              void* d_out, int out_size, void* d_ws, size_t ws_size,
                              hipStream_t stream) {
    const float* x = (const float*)d_in[0];
    float* out = (float*)d_out;
    const int n = in_sizes[0];  // 4,000,000 points
    const int grid = (n + BLK - 1) / BLK;
    bsp_prime_kernel<<<grid, BLK, 0, stream>>>(x, out, n);
}